// Round 6
// baseline (263.752 us; speedup 1.0000x reference)
//
#include <hip/hip_runtime.h>
#include <hip/hip_bf16.h>

typedef __attribute__((ext_vector_type(8))) short bf16x8;
typedef __attribute__((ext_vector_type(4))) float f32x4;
typedef __attribute__((ext_vector_type(8))) unsigned short u16x8;

#define M_DIM 4096
#define N_DIM 1024
#define IN_F  1024
#define K_DIM 12288   // IN_F * 12  (11 spline slots + 1 residual slot)
#define KS4   4
#define KPART (K_DIM / KS4)    // 3072
#define BK 64
#define NT (KPART / BK)        // 48

__device__ __forceinline__ unsigned short f2b(float v) {
  __hip_bfloat16 h = __float2bfloat16(v);
  return *reinterpret_cast<unsigned short*>(&h);
}

__device__ __forceinline__ float fast_tanh(float x) {
  // tanh(x) = 1 - 2/(1+e^{2x}); v_exp-based, ~6 VALU ops, exact at +-inf
  float e = __expf(2.0f * x);
  return 1.0f - 2.0f / (e + 1.0f);
}

// Uniform cubic B-spline, grid = linspace(-1.75, 1.75, 15), h = 0.25.
__device__ __forceinline__ void spline12(float xv, float* w) {
  float t  = fast_tanh(xv);
  float tf = (t + 1.75f) * 4.0f;          // in (3,11) since t in (-1,1)
  int j = (int)tf;
  j = j < 3 ? 3 : (j > 10 ? 10 : j);
  float u  = tf - (float)j;
  float um = 1.0f - u;
  float u2 = u * u;
  float w0 = um * um * um * (1.0f / 6.0f);
  float w1 = (0.5f * u - 1.0f) * u2 + (2.0f / 3.0f);
  float w2 = ((-0.5f * u + 0.5f) * u + 0.5f) * u + (1.0f / 6.0f);
  float w3 = u * u2 * (1.0f / 6.0f);
  int base = j - 3;                        // in [0,7]
  #pragma unroll
  for (int s = 0; s < 11; ++s) {
    int r = s - base;
    w[s] = (r == 0) ? w0 : (r == 1) ? w1 : (r == 2) ? w2 : (r == 3) ? w3 : 0.0f;
  }
  w[11] = xv;
}

// ---------------- Pass 1b: A[b][i*12+n] bf16, LDS-transposed coalesced stores ----------------
__global__ __launch_bounds__(256) void bases_kernel(const float* __restrict__ x,
                                                    unsigned short* __restrict__ A) {
  __shared__ unsigned short sb[256 * 24];   // 12 KB
  const int tid = threadIdx.x;
  int e0 = blockIdx.x * 512 + tid * 2;
  float2 xv = *(const float2*)(x + e0);
  float w0[12], w1[12];
  spline12(xv.x, w0);
  spline12(xv.y, w1);
  #pragma unroll
  for (int s = 0; s < 12; ++s) { sb[tid * 24 + s] = f2b(w0[s]); sb[tid * 24 + 12 + s] = f2b(w1[s]); }
  __syncthreads();
  u16x8* dst = (u16x8*)(A + (size_t)blockIdx.x * 512 * 12);
  const u16x8* src = (const u16x8*)sb;
  #pragma unroll
  for (int k = 0; k < 3; ++k) dst[tid + k * 256] = src[tid + k * 256];
}

// ---------------- Pass 1a: Bt[o][i*12+n] bf16 (coalesced transpose, padded LDS) ----------------
// grid (64, 16): block covers o-chunk of 16 (x), i-chunk of 64 (y).
__global__ __launch_bounds__(256) void repack_kernel(const float* __restrict__ coeffs,
                                                     const float* __restrict__ W,
                                                     unsigned short* __restrict__ Bt) {
  __shared__ float lc[64 * 180];   // [i][ol*11+n], stride 180 (16B-aligned, conflict-reduced)
  __shared__ float lw[64 * 20];    // [i][ol], stride 20
  const int o0 = blockIdx.x * 16;
  const int i0 = blockIdx.y * 64;
  const int tid = threadIdx.x;
  #pragma unroll
  for (int it = 0; it < 11; ++it) {
    int v = it * 256 + tid;            // < 2816
    int i = v / 44, c = v - i * 44;
    f32x4 d = *(const f32x4*)(coeffs + ((size_t)(i0 + i) * 1024 + o0) * 11 + c * 4);
    *(f32x4*)(lc + i * 180 + c * 4) = d;
  }
  #pragma unroll
  for (int it = 0; it < 4; ++it) {
    int e = it * 256 + tid;            // < 1024
    int i = e >> 4, ol = e & 15;
    lw[i * 20 + ol] = W[(size_t)(i0 + i) * 1024 + o0 + ol];
  }
  __syncthreads();
  #pragma unroll
  for (int it = 0; it < 6; ++it) {
    int v = it * 256 + tid;            // < 1536
    int ol = v / 96, c = v - ol * 96;
    unsigned short h[8];
    #pragma unroll
    for (int s = 0; s < 8; ++s) {
      int g = c * 8 + s;
      int i = g / 12, n = g - i * 12;
      float val = (n < 11) ? lc[i * 180 + ol * 11 + n] : lw[i * 20 + ol];
      h[s] = f2b(val);
    }
    *(u16x8*)(Bt + (size_t)(o0 + ol) * K_DIM + (size_t)i0 * 12 + c * 8) =
        (u16x8){h[0], h[1], h[2], h[3], h[4], h[5], h[6], h[7]};
  }
}

// ---------------- Pass 2: split-K GEMM, BM=BN=256, 8 waves, 2-slot ring, counted vmcnt ----
// C[4096,1024] += A[4096,K]*Bt[1024,K]^T.  256 tile, BK=64, 512 thr (2M x 4N waves,
// 128x64 per wave), 1 block/CU, LDS 128 KB.
__device__ __forceinline__ void async16(const void* g, void* l) {
  __builtin_amdgcn_global_load_lds(
      (const __attribute__((address_space(1))) void*)g,
      (__attribute__((address_space(3))) void*)l, 16, 0, 0);
}

__global__ __launch_bounds__(512, 2) void gemm_kernel(const unsigned short* __restrict__ A,
                                                      const unsigned short* __restrict__ Bt,
                                                      float* __restrict__ out) {
  // 2 slots x (A 32KB + B 32KB) = 128 KB
  __shared__ __align__(16) unsigned short lds[65536];
  char* lp = (char*)lds;
  const int AS[2] = {0, 32768};
  const int BS[2] = {65536, 98304};

  const int tid  = threadIdx.x;
  const int lane = tid & 63;
  const int wid  = tid >> 6;          // 0..7
  const int wm   = wid >> 2;          // 0..1 : M half (128 rows)
  const int wn   = wid & 3;           // 0..3 : N quarter (64 cols)

  // A-exclusive XCD map: 256 blocks; xcd owns bm in {xcd*2, xcd*2+1}
  const int blk = blockIdx.x;          // 0..255
  const int xcd = blk & 7;
  const int q   = blk >> 3;            // 0..31
  const int bm  = xcd * 2 + (q & 1);   // 0..15
  const int r2  = q >> 1;              // 0..15
  const int bn  = r2 & 3;              // 0..3
  const int ks  = r2 >> 2;             // 0..3
  const size_t m0 = (size_t)bm * 256;
  const size_t n0 = (size_t)bn * 256;
  const size_t ksbyte = (size_t)ks * KPART * 2;

  // staging: tile = [256 rows][64 k] bf16 = 2048 x 16B chunks; 4 chunks/thread/matrix.
  // LDS linear dest; global source pre-swizzled (rule #21): slot chunk cp holds cp^(row&7).
  const char* srcA[4]; const char* srcB[4]; int ldso[4];
  #pragma unroll
  for (int p = 0; p < 4; ++p) {
    int g  = p * 512 + tid;            // 0..2047
    int rr = g >> 3, cp = g & 7;
    int cs = cp ^ (rr & 7);
    srcA[p] = (const char*)A  + ((m0 + rr) * (size_t)K_DIM) * 2 + ksbyte + cs * 16;
    srcB[p] = (const char*)Bt + ((n0 + rr) * (size_t)K_DIM) * 2 + ksbyte + cs * 16;
    ldso[p] = g * 16;
  }

  auto stage = [&](int slot, int tile) {
    size_t kb = (size_t)tile * 128;    // 64 bf16 = 128 B per K-step
    #pragma unroll
    for (int p = 0; p < 4; ++p) async16(srcA[p] + kb, lp + AS[slot] + ldso[p]);
    #pragma unroll
    for (int p = 0; p < 4; ++p) async16(srcB[p] + kb, lp + BS[slot] + ldso[p]);
  };

  // ds_read byte offsets (xor-swizzled), kk=0; kk=1 is offset ^ 64 (chunk-bit 2 flip)
  int offA[8], offB[4];
  #pragma unroll
  for (int m = 0; m < 8; ++m) {
    int row = wm * 128 + m * 16 + (lane & 15);
    int ck  = (lane >> 4) ^ (row & 7);
    offA[m] = row * 128 + ck * 16;
  }
  #pragma unroll
  for (int n = 0; n < 4; ++n) {
    int rowb = wn * 64 + n * 16 + (lane & 15);
    int ckb  = (lane >> 4) ^ (rowb & 7);
    offB[n] = rowb * 128 + ckb * 16;
  }

  f32x4 acc[8][4];
  #pragma unroll
  for (int m = 0; m < 8; ++m)
    #pragma unroll
    for (int n = 0; n < 4; ++n) acc[m][n] = (f32x4){0.f, 0.f, 0.f, 0.f};

  stage(0, 0);
  stage(1, 1);

  for (int t = 0; t < NT; ++t) {
    const int cur = t & 1;
    // gate: tile t landed; tile t+1's 8 loads stay in flight across both barriers
    if (t < NT - 1) asm volatile("s_waitcnt vmcnt(8)" ::: "memory");
    else            asm volatile("s_waitcnt vmcnt(0)" ::: "memory");
    __builtin_amdgcn_s_barrier();
    __builtin_amdgcn_sched_barrier(0);
    asm volatile("" ::: "memory");

    __builtin_amdgcn_s_setprio(1);
    #pragma unroll
    for (int kk = 0; kk < 2; ++kk) {
      const int kx = kk * 64;          // swizzled-chunk XOR for kk=1
      bf16x8 a[8], b[4];
      #pragma unroll
      for (int m = 0; m < 8; ++m) a[m] = *(const bf16x8*)(lp + AS[cur] + (offA[m] ^ kx));
      #pragma unroll
      for (int n = 0; n < 4; ++n) b[n] = *(const bf16x8*)(lp + BS[cur] + (offB[n] ^ kx));
      #pragma unroll
      for (int m = 0; m < 8; ++m)
        #pragma unroll
        for (int n = 0; n < 4; ++n)
          acc[m][n] = __builtin_amdgcn_mfma_f32_16x16x32_bf16(a[m], b[n], acc[m][n], 0, 0, 0);
    }
    __builtin_amdgcn_s_setprio(0);

    asm volatile("" ::: "memory");
    __builtin_amdgcn_sched_barrier(0);
    __builtin_amdgcn_s_barrier();       // all waves done reading slot cur

    if (t + 2 < NT) stage(cur, t + 2);
  }

  const int lr = (lane >> 4) * 4;   // C/D: col=lane&15, row=(lane>>4)*4+j
  const int lc = lane & 15;
  #pragma unroll
  for (int m = 0; m < 8; ++m)
    #pragma unroll
    for (int n = 0; n < 4; ++n)
      #pragma unroll
      for (int j = 0; j < 4; ++j)
        atomicAdd(&out[(m0 + wm * 128 + m * 16 + lr + j) * N_DIM + n0 + wn * 64 + n * 16 + lc],
                  acc[m][n][j]);
}

// ---------------- Fallback (correctness insurance if ws too small) ----------------
__global__ __launch_bounds__(256) void fallback_kernel(const float* __restrict__ x,
                                                       const float* __restrict__ coeffs,
                                                       const float* __restrict__ W,
                                                       float* __restrict__ out) {
  __shared__ float bas[16][64][12];
  const int o0 = blockIdx.x * 64;
  const int b0 = blockIdx.y * 16;
  const int tid = threadIdx.x;
  const int o = tid & 63, bg = tid >> 6;
  float acc[4] = {0.f, 0.f, 0.f, 0.f};
  for (int ic = 0; ic < 16; ++ic) {
    __syncthreads();
    #pragma unroll
    for (int p = 0; p < 4; ++p) {
      int pp = tid + p * 256;
      int bb = pp >> 6, il = pp & 63;
      float w[12];
      spline12(x[(size_t)(b0 + bb) * 1024 + ic * 64 + il], w);
      #pragma unroll
      for (int n = 0; n < 12; ++n) bas[bb][il][n] = w[n];
    }
    __syncthreads();
    for (int il = 0; il < 64; ++il) {
      int gi = ic * 64 + il;
      const float* cp = coeffs + ((size_t)gi * 1024 + o0 + o) * 11;
      float cf[12];
      #pragma unroll
      for (int n = 0; n < 11; ++n) cf[n] = cp[n];
      cf[11] = W[(size_t)gi * 1024 + o0 + o];
      #pragma unroll
      for (int bb = 0; bb < 4; ++bb) {
        float s = 0.f;
        #pragma unroll
        for (int n = 0; n < 12; ++n) s += bas[bg * 4 + bb][il][n] * cf[n];
        acc[bb] += s;
      }
    }
  }
  #pragma unroll
  for (int bb = 0; bb < 4; ++bb)
    out[(size_t)(b0 + bg * 4 + bb) * 1024 + o0 + o] = acc[bb];
}

extern "C" void kernel_launch(void* const* d_in, const int* in_sizes, int n_in,
                              void* d_out, int out_size, void* d_ws, size_t ws_size,
                              hipStream_t stream) {
  const float* x      = (const float*)d_in[0];   // [4096,1024]
  const float* coeffs = (const float*)d_in[1];   // [1024,1024,11]
  const float* W      = (const float*)d_in[2];   // [1024,1024]
  float* out = (float*)d_out;

  const size_t needA = (size_t)M_DIM * K_DIM * 2;
  const size_t needB = (size_t)N_DIM * K_DIM * 2;

  if (ws_size >= needA + needB) {
    unsigned short* Abuf = (unsigned short*)d_ws;
    unsigned short* Btuf = (unsigned short*)((char*)d_ws + needA);
    hipMemsetAsync(out, 0, (size_t)out_size * sizeof(float), stream);
    bases_kernel<<<dim3(M_DIM * IN_F / 512), dim3(256), 0, stream>>>(x, Abuf);
    repack_kernel<<<dim3(64, 16), dim3(256), 0, stream>>>(coeffs, W, Btuf);
    gemm_kernel<<<dim3(256), dim3(512), 0, stream>>>(Abuf, Btuf, out);
  } else {
    fallback_kernel<<<dim3(16, 256), dim3(256), 0, stream>>>(x, coeffs, W, out);
  }
}